// Round 12
// baseline (184.284 us; speedup 1.0000x reference)
//
#include <hip/hip_runtime.h>

typedef _Float16 f16;
typedef f16 f16x4 __attribute__((ext_vector_type(4)));
typedef f16 f16x8 __attribute__((ext_vector_type(8)));
typedef float f32x16 __attribute__((ext_vector_type(16)));

#define NB 8
#define NC 128
#define NZ 4
#define NS 8
#define NT 1024
#define NH 64

#define WQ_N (NC*NZ*NS*NH)   // 262144
#define WK_N (NB*NZ*NT*NH)   // 2097152

#define OUT_CTX  (NB*NC*NZ*NS*NT)          // 33554432
#define OUT_ATTN (OUT_CTX + NB*NC*NZ*NH)   // 33816576

__device__ __forceinline__ float fast_tanh(float x) {
    // tanh(x) = 1 - 2/(exp(2x)+1); exact at saturation
    float e = __expf(2.0f * x);
    return 1.0f - 2.0f * __builtin_amdgcn_rcpf(e + 1.0f);
}

// ---------------- prep: tanh + fp16 convert (+ K transpose) ----------------
__global__ __launch_bounds__(256) void prep_kernel(
    const float* __restrict__ WQ, const float* __restrict__ WK, const float* __restrict__ K,
    f16* __restrict__ wqh, f16* __restrict__ wkh, f16* __restrict__ ktT)
{
    __shared__ f16 ldsT[64*64];
    const int tid = threadIdx.x;
    const int blk = blockIdx.x;
    if (blk < 512) {
        const int bz = blk >> 4;
        const int t0 = (blk & 15) << 6;   // 64-row t tile
        #pragma unroll
        for (int it = 0; it < 4; ++it) {
            int idx = it*256 + tid;
            int tl  = idx >> 4;      // 0..63 (t within tile)
            int seg = idx & 15;      // float4 segment of the 64-h row
            int gi  = (bz*NT + t0 + tl)*NH + seg*4;
            float4 wk4 = *(const float4*)(WK + gi);
            float4 k4  = *(const float4*)(K  + gi);
            f16x4 wv;
            wv[0] = (f16)fast_tanh(wk4.x);
            wv[1] = (f16)fast_tanh(wk4.y);
            wv[2] = (f16)fast_tanh(wk4.z);
            wv[3] = (f16)fast_tanh(wk4.w);
            *(f16x4*)(wkh + gi) = wv;
            ldsT[(seg*4+0)*64 + tl] = (f16)fast_tanh(k4.x);
            ldsT[(seg*4+1)*64 + tl] = (f16)fast_tanh(k4.y);
            ldsT[(seg*4+2)*64 + tl] = (f16)fast_tanh(k4.z);
            ldsT[(seg*4+3)*64 + tl] = (f16)fast_tanh(k4.w);
        }
        __syncthreads();
        #pragma unroll
        for (int it = 0; it < 4; ++it) {
            int idx = it*256 + tid;
            int h  = idx >> 4;
            int ts = idx & 15;
            f16x4 v = *(const f16x4*)&ldsT[h*64 + ts*4];
            *(f16x4*)(ktT + (bz*NH + h)*NT + t0 + ts*4) = v;
        }
    } else {
        const int ib = blk - 512;   // 16 blocks cover 262144 WQ elems
        #pragma unroll
        for (int it = 0; it < 16; ++it) {
            int gi = ib*16384 + it*1024 + tid*4;
            float4 q = *(const float4*)(WQ + gi);
            f16x4 w;
            w[0] = (f16)q.x; w[1] = (f16)q.y; w[2] = (f16)q.z; w[3] = (f16)q.w;
            *(f16x4*)(wqh + gi) = w;
        }
    }
}

// ---- K1: streaming scores + rowsum(exp) -> invws. 4 blocks/CU. ----------
// Per-tile acc (double-buffered, WAR-free), discarded after store+exp.
__global__ __launch_bounds__(256, 4) void scores_kernel(
    const f16* __restrict__ wqh, const f16* __restrict__ wkh,
    float* __restrict__ scores, float* __restrict__ invws)
{
    __shared__ float rsL[4][32];
    const int tid  = threadIdx.x;
    const int wave = tid >> 6;
    const int lane = tid & 63;
    const int l31  = lane & 31;
    const int g    = lane >> 5;
    const int bid  = blockIdx.x;
    const int bz = bid & 31, mt = bid >> 5;
    const int b = bz >> 2, z = bz & 3;
    const int m0 = mt * 32;

    // A fragments (WQ rows m0..m0+31), k = h = 16*st + 8*g + e
    const int mgA = m0 + l31;
    const f16* ap = wqh + (((mgA >> 3)*NZ + z)*NS + (mgA & 7))*NH + g*8;
    f16x8 afr[4];
    #pragma unroll
    for (int st = 0; st < 4; ++st) afr[st] = *(const f16x8*)(ap + st*16);

    const int base2 = ((b*NC + mt*4)*NZ + z)*NS*NT;
    float p[16];
    #pragma unroll
    for (int r = 0; r < 16; ++r) p[r] = 0.f;

    f32x16 accD[2];   // ping-pong: MFMA of tile tt+1 never overwrites stored regs

    #pragma unroll
    for (int tt = 0; tt < 8; ++tt) {
        const int t0 = (wave*8 + tt) * 32;   // wave-contiguous 256-t span
        const f16* bp = wkh + (bz*NT + t0 + l31)*NH + g*8;
        #pragma unroll
        for (int r = 0; r < 16; ++r) accD[tt & 1][r] = 0.f;
        #pragma unroll
        for (int st = 0; st < 4; ++st) {
            f16x8 bfr = *(const f16x8*)(bp + st*16);
            accD[tt & 1] = __builtin_amdgcn_mfma_f32_32x32x16_f16(afr[st], bfr, accD[tt & 1], 0, 0, 0);
        }
        const int tcol = t0 + l31;
        #pragma unroll
        for (int r = 0; r < 16; ++r) {
            float v = accD[tt & 1][r];
            scores[base2 + (r >> 2)*32768 + ((r & 3) + 4*g)*1024 + tcol] = v;
            p[r] += __expf(v);
        }
    }

    // reduce over the 32 t-columns (stays within each 32-lane half)
    #pragma unroll
    for (int d = 1; d < 32; d <<= 1)
        #pragma unroll
        for (int r = 0; r < 16; ++r) p[r] += __shfl_xor(p[r], d, 64);

    if (l31 == 0) {
        #pragma unroll
        for (int r = 0; r < 16; ++r) rsL[wave][(r & 3) + 8*(r >> 2) + 4*g] = p[r];
    }
    __syncthreads();
    if (tid < 32) invws[bz*1024 + m0 + tid] =
        1.0f / (rsL[0][tid] + rsL[1][tid] + rsL[2][tid] + rsL[3][tid]);
}

// ---- K2: recompute QK^T (bitwise-identical), attn stores + PV. 4/CU. ----
__global__ __launch_bounds__(256, 4) void attn_pv_kernel(
    const f16* __restrict__ wqh, const f16* __restrict__ wkh, const f16* __restrict__ ktT,
    const float* __restrict__ invws, float* __restrict__ attn, float* __restrict__ ctxout)
{
    __shared__ float ctxW[4][32][64];   // 32 KB; per-wave head doubles as attnB (f16[1024])
    __shared__ float invL[32];

    const int tid  = threadIdx.x;
    const int wave = tid >> 6;
    const int lane = tid & 63;
    const int l31  = lane & 31;
    const int g    = lane >> 5;
    const int bid  = blockIdx.x;
    const int bz = bid & 31, mt = bid >> 5;
    const int b = bz >> 2, z = bz & 3;
    const int m0 = mt * 32;

    f16* attnB = (f16*)&ctxW[wave][0][0];   // 2 KB region, wave-private

    if (tid < 32) invL[tid] = invws[bz*1024 + m0 + tid];
    __syncthreads();

    // A fragments (same as K1 -> identical MFMA results)
    const int mgA = m0 + l31;
    const f16* ap = wqh + (((mgA >> 3)*NZ + z)*NS + (mgA & 7))*NH + g*8;
    f16x8 afr[4];
    #pragma unroll
    for (int st = 0; st < 4; ++st) afr[st] = *(const f16x8*)(ap + st*16);

    const int base2 = ((b*NC + mt*4)*NZ + z)*NS*NT;

    f32x16 cacc[2];
    #pragma unroll
    for (int nt = 0; nt < 2; ++nt)
        #pragma unroll
        for (int r = 0; r < 16; ++r) cacc[nt][r] = 0.f;

    #pragma unroll
    for (int tt = 0; tt < 8; ++tt) {
        const int t0 = (wave*8 + tt) * 32;
        // B-fragment loads for PV issued FIRST (vmcnt in-order: the PV MFMA's
        // wait covers only these, not the younger attn stores)
        f16x8 bfr2[2][2];
        #pragma unroll
        for (int s2 = 0; s2 < 2; ++s2)
            #pragma unroll
            for (int nt = 0; nt < 2; ++nt)
                bfr2[s2][nt] = *(const f16x8*)(ktT + (bz*NH + nt*32 + l31)*NT + t0 + s2*16 + g*8);

        // recompute QK^T tile
        const f16* bp = wkh + (bz*NT + t0 + l31)*NH + g*8;
        f32x16 acc;
        #pragma unroll
        for (int r = 0; r < 16; ++r) acc[r] = 0.f;
        #pragma unroll
        for (int st = 0; st < 4; ++st) {
            f16x8 bfr = *(const f16x8*)(bp + st*16);
            acc = __builtin_amdgcn_mfma_f32_32x32x16_f16(afr[st], bfr, acc, 0, 0, 0);
        }

        const int tcol = t0 + l31;
        #pragma unroll
        for (int r = 0; r < 16; ++r) {
            int ml = (r & 3) + 8*(r >> 2) + 4*g;
            float a = __expf(acc[r]) * invL[ml];
            attn[base2 + (r >> 2)*32768 + ((r & 3) + 4*g)*1024 + tcol] = a;
            int tbk = l31 >> 3;
            int ai = ((tbk*32 + ml)*8 + (l31 & 7)) ^ (tbk << 3);
            attnB[ai] = (f16)a;
        }
        // PV: A = attn tile (k = t), B = Kt
        #pragma unroll
        for (int s2 = 0; s2 < 2; ++s2) {
            int tbk = 2*s2 + g;
            int ai = ((tbk*32 + l31)*8) ^ (tbk << 3);
            f16x8 pa = *(const f16x8*)&attnB[ai];
            #pragma unroll
            for (int nt = 0; nt < 2; ++nt)
                cacc[nt] = __builtin_amdgcn_mfma_f32_32x32x16_f16(pa, bfr2[s2][nt], cacc[nt], 0, 0, 0);
        }
    }

    // barrier before ctxW writes (ctxW aliases attnB memory; keeps the f16
    // reads and f32 writes strictly ordered across the type-punned region)
    __syncthreads();

    #pragma unroll
    for (int nt = 0; nt < 2; ++nt) {
        #pragma unroll
        for (int r = 0; r < 16; ++r) {
            int ml = (r & 3) + 8*(r >> 2) + 4*g;
            ctxW[wave][ml][nt*32 + l31] = cacc[nt][r];
        }
    }
    __syncthreads();

    // context = mean over s (and sum over waves' t-partitions)
    {
        int cl = tid >> 6;      // 0..3 local c
        int h  = tid & 63;
        float sum = 0.f;
        #pragma unroll
        for (int w = 0; w < 4; ++w)
            #pragma unroll
            for (int q = 0; q < 8; ++q)
                sum += ctxW[w][cl*8 + q][h];
        ctxout[((b*NC + (m0 >> 3) + cl)*NZ + z)*NH + h] = sum * 0.125f;
    }
}

extern "C" void kernel_launch(void* const* d_in, const int* in_sizes, int n_in,
                              void* d_out, int out_size, void* d_ws, size_t ws_size,
                              hipStream_t stream)
{
    const float* WQ = (const float*)d_in[0];
    const float* WK = (const float*)d_in[1];
    const float* K  = (const float*)d_in[2];

    char* ws = (char*)d_ws;
    f16* wqh = (f16*)(ws);
    f16* wkh = (f16*)(ws + (size_t)WQ_N*2);
    f16* ktT = (f16*)(ws + (size_t)WQ_N*2 + (size_t)WK_N*2);
    float* invws = (float*)(ws + (size_t)WQ_N*2 + (size_t)WK_N*4);

    float* out    = (float*)d_out;
    float* scores = out;
    float* ctxout = out + OUT_CTX;
    float* attn   = out + OUT_ATTN;

    hipLaunchKernelGGL(prep_kernel, dim3(528), dim3(256), 0, stream,
                       WQ, WK, K, wqh, wkh, ktT);
    hipLaunchKernelGGL(scores_kernel, dim3(1024), dim3(256), 0, stream,
                       wqh, wkh, scores, invws);
    hipLaunchKernelGGL(attn_pv_kernel, dim3(1024), dim3(256), 0, stream,
                       wqh, wkh, ktT, invws, attn, ctxout);
}

// Round 13
// 110.409 us; speedup vs baseline: 1.6691x; 1.6691x over previous
//
#include <hip/hip_runtime.h>

typedef _Float16 f16;
typedef f16 f16x4 __attribute__((ext_vector_type(4)));
typedef f16 f16x8 __attribute__((ext_vector_type(8)));
typedef float f32x16 __attribute__((ext_vector_type(16)));

#define NB 8
#define NC 128
#define NZ 4
#define NS 8
#define NT 1024
#define NH 64

#define WQ_N (NC*NZ*NS*NH)   // 262144
#define WK_N (NB*NZ*NT*NH)   // 2097152

#define OUT_CTX  (NB*NC*NZ*NS*NT)          // 33554432
#define OUT_ATTN (OUT_CTX + NB*NC*NZ*NH)   // 33816576

__device__ __forceinline__ float fast_tanh(float x) {
    // tanh(x) = 1 - 2/(exp(2x)+1); exact at saturation
    float e = __expf(2.0f * x);
    return 1.0f - 2.0f * __builtin_amdgcn_rcpf(e + 1.0f);
}

// ---------------- prep: tanh + fp16 convert (+ K transpose) ----------------
__global__ __launch_bounds__(256) void prep_kernel(
    const float* __restrict__ WQ, const float* __restrict__ WK, const float* __restrict__ K,
    f16* __restrict__ wqh, f16* __restrict__ wkh, f16* __restrict__ ktT)
{
    __shared__ f16 ldsT[64*64];
    const int tid = threadIdx.x;
    const int blk = blockIdx.x;
    if (blk < 512) {
        const int bz = blk >> 4;
        const int t0 = (blk & 15) << 6;   // 64-row t tile
        #pragma unroll
        for (int it = 0; it < 4; ++it) {
            int idx = it*256 + tid;
            int tl  = idx >> 4;      // 0..63 (t within tile)
            int seg = idx & 15;      // float4 segment of the 64-h row
            int gi  = (bz*NT + t0 + tl)*NH + seg*4;
            float4 wk4 = *(const float4*)(WK + gi);
            float4 k4  = *(const float4*)(K  + gi);
            f16x4 wv;
            wv[0] = (f16)fast_tanh(wk4.x);
            wv[1] = (f16)fast_tanh(wk4.y);
            wv[2] = (f16)fast_tanh(wk4.z);
            wv[3] = (f16)fast_tanh(wk4.w);
            *(f16x4*)(wkh + gi) = wv;
            ldsT[(seg*4+0)*64 + tl] = (f16)fast_tanh(k4.x);
            ldsT[(seg*4+1)*64 + tl] = (f16)fast_tanh(k4.y);
            ldsT[(seg*4+2)*64 + tl] = (f16)fast_tanh(k4.z);
            ldsT[(seg*4+3)*64 + tl] = (f16)fast_tanh(k4.w);
        }
        __syncthreads();
        #pragma unroll
        for (int it = 0; it < 4; ++it) {
            int idx = it*256 + tid;
            int h  = idx >> 4;
            int ts = idx & 15;
            f16x4 v = *(const f16x4*)&ldsT[h*64 + ts*4];
            *(f16x4*)(ktT + (bz*NH + h)*NT + t0 + ts*4) = v;
        }
    } else {
        const int ib = blk - 512;   // 16 blocks cover 262144 WQ elems
        #pragma unroll
        for (int it = 0; it < 16; ++it) {
            int gi = ib*16384 + it*1024 + tid*4;
            float4 q = *(const float4*)(WQ + gi);
            f16x4 w;
            w[0] = (f16)q.x; w[1] = (f16)q.y; w[2] = (f16)q.z; w[3] = (f16)q.w;
            *(f16x4*)(wqh + gi) = w;
        }
    }
}

// ---- K1: streaming scores + rowsum(exp) -> invws. 4 blocks/CU. ----------
// Per-tile acc (double-buffered, WAR-free), discarded after store+exp.
__global__ __launch_bounds__(256, 4) void scores_kernel(
    const f16* __restrict__ wqh, const f16* __restrict__ wkh,
    float* __restrict__ scores, float* __restrict__ invws)
{
    __shared__ float rsL[4][32];
    const int tid  = threadIdx.x;
    const int wave = tid >> 6;
    const int lane = tid & 63;
    const int l31  = lane & 31;
    const int g    = lane >> 5;
    const int bid  = blockIdx.x;
    const int bz = bid & 31, mt = bid >> 5;
    const int b = bz >> 2, z = bz & 3;
    const int m0 = mt * 32;

    // A fragments (WQ rows m0..m0+31), k = h = 16*st + 8*g + e
    const int mgA = m0 + l31;
    const f16* ap = wqh + (((mgA >> 3)*NZ + z)*NS + (mgA & 7))*NH + g*8;
    f16x8 afr[4];
    #pragma unroll
    for (int st = 0; st < 4; ++st) afr[st] = *(const f16x8*)(ap + st*16);

    const int base2 = ((b*NC + mt*4)*NZ + z)*NS*NT;
    float p[16];
    #pragma unroll
    for (int r = 0; r < 16; ++r) p[r] = 0.f;

    f32x16 accD[2];   // ping-pong: MFMA of tile tt+1 never overwrites stored regs

    #pragma unroll
    for (int tt = 0; tt < 8; ++tt) {
        const int t0 = (wave*8 + tt) * 32;   // wave-contiguous 256-t span
        const f16* bp = wkh + (bz*NT + t0 + l31)*NH + g*8;
        #pragma unroll
        for (int r = 0; r < 16; ++r) accD[tt & 1][r] = 0.f;
        #pragma unroll
        for (int st = 0; st < 4; ++st) {
            f16x8 bfr = *(const f16x8*)(bp + st*16);
            accD[tt & 1] = __builtin_amdgcn_mfma_f32_32x32x16_f16(afr[st], bfr, accD[tt & 1], 0, 0, 0);
        }
        const int tcol = t0 + l31;
        #pragma unroll
        for (int r = 0; r < 16; ++r) {
            float v = accD[tt & 1][r];
            scores[base2 + (r >> 2)*32768 + ((r & 3) + 4*g)*1024 + tcol] = v;
            p[r] += __expf(v);
        }
    }

    // reduce over the 32 t-columns (stays within each 32-lane half)
    #pragma unroll
    for (int d = 1; d < 32; d <<= 1)
        #pragma unroll
        for (int r = 0; r < 16; ++r) p[r] += __shfl_xor(p[r], d, 64);

    if (l31 == 0) {
        #pragma unroll
        for (int r = 0; r < 16; ++r) rsL[wave][(r & 3) + 8*(r >> 2) + 4*g] = p[r];
    }
    __syncthreads();
    if (tid < 32) invws[bz*1024 + m0 + tid] =
        1.0f / (rsL[0][tid] + rsL[1][tid] + rsL[2][tid] + rsL[3][tid]);
}

// ---- K2: recompute QK^T (bitwise-identical), attn stores + PV. ----------
// (256,3): reg cap ~170 fits the ~120 live regs WITHOUT spilling (R12's
// (256,4) cap of 128 split 64 VGPR + 64 AGPR and thrashed scratch:
// FETCH 116MB, WRITE 330MB, 27ms).
__global__ __launch_bounds__(256, 3) void attn_pv_kernel(
    const f16* __restrict__ wqh, const f16* __restrict__ wkh, const f16* __restrict__ ktT,
    const float* __restrict__ invws, float* __restrict__ attn, float* __restrict__ ctxout)
{
    __shared__ float ctxW[4][32][64];   // 32 KB
    __shared__ f16   attnB[4][1024];    // 8 KB, per-wave blocked+XOR layout
    __shared__ float invL[32];

    const int tid  = threadIdx.x;
    const int wave = tid >> 6;
    const int lane = tid & 63;
    const int l31  = lane & 31;
    const int g    = lane >> 5;
    const int bid  = blockIdx.x;
    const int bz = bid & 31, mt = bid >> 5;
    const int b = bz >> 2, z = bz & 3;
    const int m0 = mt * 32;

    if (tid < 32) invL[tid] = invws[bz*1024 + m0 + tid];
    __syncthreads();

    // A fragments (same as K1 -> identical MFMA results)
    const int mgA = m0 + l31;
    const f16* ap = wqh + (((mgA >> 3)*NZ + z)*NS + (mgA & 7))*NH + g*8;
    f16x8 afr[4];
    #pragma unroll
    for (int st = 0; st < 4; ++st) afr[st] = *(const f16x8*)(ap + st*16);

    const int base2 = ((b*NC + mt*4)*NZ + z)*NS*NT;

    f32x16 cacc[2];
    #pragma unroll
    for (int nt = 0; nt < 2; ++nt)
        #pragma unroll
        for (int r = 0; r < 16; ++r) cacc[nt][r] = 0.f;

    #pragma unroll
    for (int tt = 0; tt < 8; ++tt) {
        const int t0 = (wave*8 + tt) * 32;
        // B-fragment loads for PV issued FIRST (vmcnt in-order: the PV MFMA's
        // wait covers only these, not the younger attn stores)
        f16x8 bfr2[2][2];
        #pragma unroll
        for (int s2 = 0; s2 < 2; ++s2)
            #pragma unroll
            for (int nt = 0; nt < 2; ++nt)
                bfr2[s2][nt] = *(const f16x8*)(ktT + (bz*NH + nt*32 + l31)*NT + t0 + s2*16 + g*8);

        // recompute QK^T tile
        const f16* bp = wkh + (bz*NT + t0 + l31)*NH + g*8;
        f32x16 acc;
        #pragma unroll
        for (int r = 0; r < 16; ++r) acc[r] = 0.f;
        #pragma unroll
        for (int st = 0; st < 4; ++st) {
            f16x8 bfr = *(const f16x8*)(bp + st*16);
            acc = __builtin_amdgcn_mfma_f32_32x32x16_f16(afr[st], bfr, acc, 0, 0, 0);
        }

        const int tcol = t0 + l31;
        #pragma unroll
        for (int r = 0; r < 16; ++r) {
            int ml = (r & 3) + 8*(r >> 2) + 4*g;
            float a = __expf(acc[r]) * invL[ml];
            attn[base2 + (r >> 2)*32768 + ((r & 3) + 4*g)*1024 + tcol] = a;
            int tbk = l31 >> 3;
            int ai = ((tbk*32 + ml)*8 + (l31 & 7)) ^ (tbk << 3);
            attnB[wave][ai] = (f16)a;
        }
        // PV: A = attn tile (k = t), B = Kt
        #pragma unroll
        for (int s2 = 0; s2 < 2; ++s2) {
            int tbk = 2*s2 + g;
            int ai = ((tbk*32 + l31)*8) ^ (tbk << 3);
            f16x8 pa = *(const f16x8*)&attnB[wave][ai];
            #pragma unroll
            for (int nt = 0; nt < 2; ++nt)
                cacc[nt] = __builtin_amdgcn_mfma_f32_32x32x16_f16(pa, bfr2[s2][nt], cacc[nt], 0, 0, 0);
        }
    }

    #pragma unroll
    for (int nt = 0; nt < 2; ++nt) {
        #pragma unroll
        for (int r = 0; r < 16; ++r) {
            int ml = (r & 3) + 8*(r >> 2) + 4*g;
            ctxW[wave][ml][nt*32 + l31] = cacc[nt][r];
        }
    }
    __syncthreads();

    // context = mean over s (and sum over waves' t-partitions)
    {
        int cl = tid >> 6;      // 0..3 local c
        int h  = tid & 63;
        float sum = 0.f;
        #pragma unroll
        for (int w = 0; w < 4; ++w)
            #pragma unroll
            for (int q = 0; q < 8; ++q)
                sum += ctxW[w][cl*8 + q][h];
        ctxout[((b*NC + (m0 >> 3) + cl)*NZ + z)*NH + h] = sum * 0.125f;
    }
}

extern "C" void kernel_launch(void* const* d_in, const int* in_sizes, int n_in,
                              void* d_out, int out_size, void* d_ws, size_t ws_size,
                              hipStream_t stream)
{
    const float* WQ = (const float*)d_in[0];
    const float* WK = (const float*)d_in[1];
    const float* K  = (const float*)d_in[2];

    char* ws = (char*)d_ws;
    f16* wqh = (f16*)(ws);
    f16* wkh = (f16*)(ws + (size_t)WQ_N*2);
    f16* ktT = (f16*)(ws + (size_t)WQ_N*2 + (size_t)WK_N*2);
    float* invws = (float*)(ws + (size_t)WQ_N*2 + (size_t)WK_N*4);

    float* out    = (float*)d_out;
    float* scores = out;
    float* ctxout = out + OUT_CTX;
    float* attn   = out + OUT_ATTN;

    hipLaunchKernelGGL(prep_kernel, dim3(528), dim3(256), 0, stream,
                       WQ, WK, K, wqh, wkh, ktT);
    hipLaunchKernelGGL(scores_kernel, dim3(1024), dim3(256), 0, stream,
                       wqh, wkh, scores, invws);
    hipLaunchKernelGGL(attn_pv_kernel, dim3(1024), dim3(256), 0, stream,
                       wqh, wkh, ktT, invws, attn, ctxout);
}

// Round 14
// 69.393 us; speedup vs baseline: 2.6557x; 1.5911x over previous
//
#include <hip/hip_runtime.h>

typedef _Float16 f16;
typedef f16 f16x4 __attribute__((ext_vector_type(4)));
typedef f16 f16x8 __attribute__((ext_vector_type(8)));
typedef float f32x16 __attribute__((ext_vector_type(16)));

#define NB 8
#define NC 128
#define NZ 4
#define NS 8
#define NT 1024
#define NH 64

#define WQ_N (NC*NZ*NS*NH)   // 262144
#define WK_N (NB*NZ*NT*NH)   // 2097152

#define OUT_CTX  (NB*NC*NZ*NS*NT)          // 33554432
#define OUT_ATTN (OUT_CTX + NB*NC*NZ*NH)   // 33816576

__device__ __forceinline__ float fast_tanh(float x) {
    // tanh(x) = 1 - 2/(exp(2x)+1); exact at saturation
    float e = __expf(2.0f * x);
    return 1.0f - 2.0f * __builtin_amdgcn_rcpf(e + 1.0f);
}

// ---------------- prep: tanh + fp16 convert (+ K transpose) ----------------
__global__ __launch_bounds__(256) void prep_kernel(
    const float* __restrict__ WQ, const float* __restrict__ WK, const float* __restrict__ K,
    f16* __restrict__ wqh, f16* __restrict__ wkh, f16* __restrict__ ktT)
{
    __shared__ f16 ldsT[64*64];
    const int tid = threadIdx.x;
    const int blk = blockIdx.x;
    if (blk < 512) {
        const int bz = blk >> 4;
        const int t0 = (blk & 15) << 6;   // 64-row t tile
        #pragma unroll
        for (int it = 0; it < 4; ++it) {
            int idx = it*256 + tid;
            int tl  = idx >> 4;      // 0..63 (t within tile)
            int seg = idx & 15;      // float4 segment of the 64-h row
            int gi  = (bz*NT + t0 + tl)*NH + seg*4;
            float4 wk4 = *(const float4*)(WK + gi);
            float4 k4  = *(const float4*)(K  + gi);
            f16x4 wv;
            wv[0] = (f16)fast_tanh(wk4.x);
            wv[1] = (f16)fast_tanh(wk4.y);
            wv[2] = (f16)fast_tanh(wk4.z);
            wv[3] = (f16)fast_tanh(wk4.w);
            *(f16x4*)(wkh + gi) = wv;
            ldsT[(seg*4+0)*64 + tl] = (f16)fast_tanh(k4.x);
            ldsT[(seg*4+1)*64 + tl] = (f16)fast_tanh(k4.y);
            ldsT[(seg*4+2)*64 + tl] = (f16)fast_tanh(k4.z);
            ldsT[(seg*4+3)*64 + tl] = (f16)fast_tanh(k4.w);
        }
        __syncthreads();
        #pragma unroll
        for (int it = 0; it < 4; ++it) {
            int idx = it*256 + tid;
            int h  = idx >> 4;
            int ts = idx & 15;
            f16x4 v = *(const f16x4*)&ldsT[h*64 + ts*4];
            *(f16x4*)(ktT + (bz*NH + h)*NT + t0 + ts*4) = v;
        }
    } else {
        const int ib = blk - 512;   // 16 blocks cover 262144 WQ elems
        #pragma unroll
        for (int it = 0; it < 16; ++it) {
            int gi = ib*16384 + it*1024 + tid*4;
            float4 q = *(const float4*)(WQ + gi);
            f16x4 w;
            w[0] = (f16)q.x; w[1] = (f16)q.y; w[2] = (f16)q.z; w[3] = (f16)q.w;
            *(f16x4*)(wqh + gi) = w;
        }
    }
}

// -------- fused: QK^T + scores-write + softmax + attn-write + PV ----------
// Best measured configuration (69.45 us): register-resident 32x1024 strip,
// 2 blocks/CU, wave-contiguous t-spans, LDS-transposed dwordx4 stores,
// load-before-store in phase 2, f16 attnB PV path.
__global__ __launch_bounds__(256, 2) void fused_kernel(
    const f16* __restrict__ wqh, const f16* __restrict__ wkh, const f16* __restrict__ ktT,
    float* __restrict__ scores, float* __restrict__ attn, float* __restrict__ ctxout)
{
    __shared__ float rsL[4][32];
    __shared__ float invL[32];
    __shared__ float tileT[4][2][1024];     // per-wave ping-pong 32x32 f32, XOR-swizzled
    __shared__ f16   attnB[4][1024];        // per-wave 32m x 32t f16, blocked+XOR layout
    __shared__ float ctxW[4][32][64];       // per-wave partial context

    const int tid  = threadIdx.x;
    const int wave = tid >> 6;
    const int lane = tid & 63;
    const int l31  = lane & 31;
    const int g    = lane >> 5;
    const int bid  = blockIdx.x;
    const int bz = bid & 31, mt = bid >> 5;
    const int b = bz >> 2, z = bz & 3;
    const int m0 = mt * 32;

    // per-thread float4 read/store geometry for the transposed tile
    const int srow = lane >> 3;             // 0..7 (s index within pass)
    const int scol = (lane & 7) * 4;        // float4 column
    const int sxor = scol ^ (srow << 2);    // XOR-swizzled column

    // ---- A fragments (WQ rows m0..m0+31), k = h = 16*st + 8*g + e ----
    const int mgA = m0 + l31;
    const f16* ap = wqh + (((mgA >> 3)*NZ + z)*NS + (mgA & 7))*NH + g*8;
    f16x8 afr[4];
    #pragma unroll
    for (int st = 0; st < 4; ++st) afr[st] = *(const f16x8*)(ap + st*16);

    // ---- phase 1a: QK^T, full 32-row strip register-resident ----
    f32x16 acc[8];
    #pragma unroll
    for (int tt = 0; tt < 8; ++tt)
        #pragma unroll
        for (int r = 0; r < 16; ++r) acc[tt][r] = 0.f;

    #pragma unroll
    for (int tt = 0; tt < 8; ++tt) {
        const int t0 = (wave*8 + tt) * 32;
        const f16* bp = wkh + (bz*NT + t0 + l31)*NH + g*8;
        #pragma unroll
        for (int st = 0; st < 4; ++st) {
            f16x8 bfr = *(const f16x8*)(bp + st*16);
            acc[tt] = __builtin_amdgcn_mfma_f32_32x32x16_f16(afr[st], bfr, acc[tt], 0, 0, 0);
        }
    }

    // ---- phase 1b: LDS-transpose -> dwordx4 scores stores + rowsum(exp) ----
    const int base2 = ((b*NC + mt*4)*NZ + z)*NS*NT;
    float p[16];
    #pragma unroll
    for (int r = 0; r < 16; ++r) p[r] = 0.f;

    #pragma unroll
    for (int tt = 0; tt < 8; ++tt) {
        const int t0 = (wave*8 + tt) * 32;
        float* tb = tileT[wave][tt & 1];
        #pragma unroll
        for (int r = 0; r < 16; ++r) {
            int ml = (r & 3) + 8*(r >> 2) + 4*g;
            tb[ml*32 + (l31 ^ (((r & 3) + 4*g) << 2))] = acc[tt][r];
            p[r] += __expf(acc[tt][r]);
        }
        __builtin_amdgcn_s_waitcnt(0xc07f);   // lgkmcnt(0): wave-private LDS, no barrier
        #pragma unroll
        for (int q = 0; q < 4; ++q) {
            float4 v = *(float4*)&tb[(q*8 + srow)*32 + sxor];
            *(float4*)(scores + base2 + q*32768 + srow*1024 + t0 + scol) = v;
        }
    }

    // reduce over the 32 t-columns (stays within each 32-lane half)
    #pragma unroll
    for (int d = 1; d < 32; d <<= 1)
        #pragma unroll
        for (int r = 0; r < 16; ++r) p[r] += __shfl_xor(p[r], d, 64);

    if (l31 == 0) {
        #pragma unroll
        for (int r = 0; r < 16; ++r) rsL[wave][(r & 3) + 8*(r >> 2) + 4*g] = p[r];
    }
    __syncthreads();
    if (tid < 32) invL[tid] = 1.0f / (rsL[0][tid] + rsL[1][tid] + rsL[2][tid] + rsL[3][tid]);
    __syncthreads();

    // ---- phase 2: attn = exp*inv -> LDS transpose + dwordx4 stores, PV ----
    f32x16 cacc[2];
    #pragma unroll
    for (int nt = 0; nt < 2; ++nt)
        #pragma unroll
        for (int r = 0; r < 16; ++r) cacc[nt][r] = 0.f;

    #pragma unroll
    for (int tt = 0; tt < 8; ++tt) {
        const int t0 = (wave*8 + tt) * 32;
        // issue B-fragment loads FIRST (vmcnt in-order: MFMA's wait covers
        // only these loads, not the younger attn stores)
        f16x8 bfr2[2][2];
        #pragma unroll
        for (int s2 = 0; s2 < 2; ++s2)
            #pragma unroll
            for (int nt = 0; nt < 2; ++nt)
                bfr2[s2][nt] = *(const f16x8*)(ktT + (bz*NH + nt*32 + l31)*NT + t0 + s2*16 + g*8);

        float* tb = tileT[wave][tt & 1];
        #pragma unroll
        for (int r = 0; r < 16; ++r) {
            int ml = (r & 3) + 8*(r >> 2) + 4*g;
            float a = __expf(acc[tt][r]) * invL[ml];
            tb[ml*32 + (l31 ^ (((r & 3) + 4*g) << 2))] = a;
            int tbk = l31 >> 3;
            int ai = ((tbk*32 + ml)*8 + (l31 & 7)) ^ (tbk << 3);
            attnB[wave][ai] = (f16)a;
        }
        __builtin_amdgcn_s_waitcnt(0xc07f);   // lgkmcnt(0)
        #pragma unroll
        for (int q = 0; q < 4; ++q) {
            float4 v = *(float4*)&tb[(q*8 + srow)*32 + sxor];
            *(float4*)(attn + base2 + q*32768 + srow*1024 + t0 + scol) = v;
        }
        // PV: A = attn tile (k = t), B = Kt
        #pragma unroll
        for (int s2 = 0; s2 < 2; ++s2) {
            int tbk = 2*s2 + g;
            int ai = ((tbk*32 + l31)*8) ^ (tbk << 3);
            f16x8 pa = *(const f16x8*)&attnB[wave][ai];
            #pragma unroll
            for (int nt = 0; nt < 2; ++nt)
                cacc[nt] = __builtin_amdgcn_mfma_f32_32x32x16_f16(pa, bfr2[s2][nt], cacc[nt], 0, 0, 0);
        }
    }

    // ---- per-wave partial context to LDS ----
    #pragma unroll
    for (int nt = 0; nt < 2; ++nt) {
        #pragma unroll
        for (int r = 0; r < 16; ++r) {
            int ml = (r & 3) + 8*(r >> 2) + 4*g;
            ctxW[wave][ml][nt*32 + l31] = cacc[nt][r];
        }
    }
    __syncthreads();

    // ---- context = mean over s (and sum over waves' t-partitions) ----
    {
        int cl = tid >> 6;      // 0..3 local c
        int h  = tid & 63;
        float sum = 0.f;
        #pragma unroll
        for (int w = 0; w < 4; ++w)
            #pragma unroll
            for (int q = 0; q < 8; ++q)
                sum += ctxW[w][cl*8 + q][h];
        ctxout[((b*NC + (m0 >> 3) + cl)*NZ + z)*NH + h] = sum * 0.125f;
    }
}

extern "C" void kernel_launch(void* const* d_in, const int* in_sizes, int n_in,
                              void* d_out, int out_size, void* d_ws, size_t ws_size,
                              hipStream_t stream)
{
    const float* WQ = (const float*)d_in[0];
    const float* WK = (const float*)d_in[1];
    const float* K  = (const float*)d_in[2];

    char* ws = (char*)d_ws;
    f16* wqh = (f16*)(ws);
    f16* wkh = (f16*)(ws + (size_t)WQ_N*2);
    f16* ktT = (f16*)(ws + (size_t)WQ_N*2 + (size_t)WK_N*2);

    float* out    = (float*)d_out;
    float* scores = out;
    float* ctxout = out + OUT_CTX;
    float* attn   = out + OUT_ATTN;

    hipLaunchKernelGGL(prep_kernel, dim3(528), dim3(256), 0, stream,
                       WQ, WK, K, wqh, wkh, ktT);
    hipLaunchKernelGGL(fused_kernel, dim3(1024), dim3(256), 0, stream,
                       wqh, wkh, ktT, scores, attn, ctxout);
}